// Round 8
// baseline (136.561 us; speedup 1.0000x reference)
//
#include <hip/hip_runtime.h>
#include <cstdint>

typedef __attribute__((ext_vector_type(8))) _Float16 f16x8;
typedef __attribute__((ext_vector_type(4))) float f32x4;

union H2 { uint32_t u; _Float16 h[2]; };

__device__ __forceinline__ void gl_lds16(const void* g, void* lds) {
  __builtin_amdgcn_global_load_lds(
      (const __attribute__((address_space(1))) char*)g,
      (__attribute__((address_space(3))) char*)lds,
      16, 0, 0);
}

// ---- features f32 -> f16 ----
__global__ __launch_bounds__(256) void k_convf(const float* __restrict__ in,
                                               _Float16* __restrict__ out) {
  size_t i = ((size_t)blockIdx.x * 256 + threadIdx.x) * 8;
  float4 a = *(const float4*)(in + i);
  float4 b = *(const float4*)(in + i + 4);
  f16x8 o;
  o[0] = (_Float16)a.x; o[1] = (_Float16)a.y; o[2] = (_Float16)a.z; o[3] = (_Float16)a.w;
  o[4] = (_Float16)b.x; o[5] = (_Float16)b.y; o[6] = (_Float16)b.z; o[7] = (_Float16)b.w;
  *(f16x8*)(out + i) = o;
}

// ---- W (1024 x 1023 f32) -> Wt (1024 x 1024 f16), Wt[n][k] = W[k][n], row 1023 = 0 ----
__global__ __launch_bounds__(256) void k_convw(const float* __restrict__ W,
                                               _Float16* __restrict__ Wt) {
  __shared__ float tile[64][65];
  int bx = blockIdx.x & 15;   // n tile
  int by = blockIdx.x >> 4;   // k tile
  int n0 = bx * 64, k0 = by * 64;
  int tx = threadIdx.x & 63, ty = threadIdx.x >> 6;
#pragma unroll
  for (int r = 0; r < 16; ++r) {
    int kl = ty * 16 + r;
    int n = n0 + tx;
    tile[kl][tx] = (n < 1023) ? W[(size_t)(k0 + kl) * 1023 + n] : 0.0f;
  }
  __syncthreads();
#pragma unroll
  for (int r = 0; r < 16; ++r) {
    int nl = ty * 16 + r;
    Wt[(size_t)(n0 + nl) * 1024 + k0 + tx] = (_Float16)tile[tx][nl];
  }
}

// ---- leaf_logits (1024 x 64 f32) -> LLt (64 x 1024 f16), LLt[a][l] = LL[l][a] ----
__global__ __launch_bounds__(256) void k_convll(const float* __restrict__ LL,
                                                _Float16* __restrict__ LLt) {
  int a = blockIdx.x;
  int t = threadIdx.x;
#pragma unroll
  for (int j = 0; j < 4; ++j) {
    int l = t + j * 256;
    LLt[(size_t)a * 1024 + l] = (_Float16)LL[(size_t)l * 64 + a];
  }
}

// ---- GEMM1: p/q = sigmoid(features @ W + b), packed f16 pair per node ----
// 128x128 tile, BK=64, 4 waves (2x2), mfma_f32_16x16x32_f16
__global__ __launch_bounds__(256) void k_gemm1(
    const _Float16* __restrict__ fA,   // [8192][1024]
    const _Float16* __restrict__ Wt,   // [1024][1024]
    const float* __restrict__ bv,      // [1023]
    uint32_t* __restrict__ pq)         // [8192][1024] packed {p,q}
{
  __shared__ __align__(16) unsigned char As[16384];
  __shared__ __align__(16) unsigned char Bs[16384];
  const int bid = blockIdx.x;
  const int id = (bid & 7) * 64 + (bid >> 3);       // XCD swizzle (512 % 8 == 0)
  const int mt = id >> 3, nt = id & 7;
  const int m0 = mt * 128, n0 = nt * 128;
  const int tid = threadIdx.x;
  const int wid = tid >> 6, lane = tid & 63;
  const int wm = wid >> 1, wn = wid & 1;
  const int lr = lane & 15, lh = lane >> 4;

  f32x4 acc[4][4];
  for (int i = 0; i < 4; ++i)
    for (int j = 0; j < 4; ++j)
      acc[i][j] = (f32x4)(0.0f);

  // staging: LDS slot chunk (i, c) holds global chunk (i, c ^ (i&7)); linear LDS dest,
  // inverse-swizzled per-lane global source (rule #21)
  const _Float16* srcA[4]; const _Float16* srcB[4];
  unsigned char *dstA[4], *dstB[4];
#pragma unroll
  for (int j = 0; j < 4; ++j) {
    int blk = j * 4 + wid;          // 0..15
    int q = blk * 64 + lane;        // chunk id 0..1023
    int i = q >> 3, c = q & 7;
    int cs = c ^ (i & 7);
    srcA[j] = fA + (size_t)(m0 + i) * 1024 + cs * 8;
    srcB[j] = Wt + (size_t)(n0 + i) * 1024 + cs * 8;
    dstA[j] = As + blk * 1024;
    dstB[j] = Bs + blk * 1024;
  }
  const int slot0 = ((0 + lh) ^ (lr & 7)) * 16;   // (row&7) == (lr&7)
  const int slot1 = ((4 + lh) ^ (lr & 7)) * 16;

  for (int kt = 0; kt < 16; ++kt) {
    __syncthreads();
#pragma unroll
    for (int j = 0; j < 4; ++j) gl_lds16(srcA[j] + kt * 64, dstA[j]);
#pragma unroll
    for (int j = 0; j < 4; ++j) gl_lds16(srcB[j] + kt * 64, dstB[j]);
    __syncthreads();
#pragma unroll
    for (int ph = 0; ph < 2; ++ph) {
      const int sb = ph ? slot1 : slot0;
      f16x8 af[4], bf[4];
#pragma unroll
      for (int mf = 0; mf < 4; ++mf)
        af[mf] = *(const f16x8*)(As + (wm * 64 + mf * 16 + lr) * 128 + sb);
#pragma unroll
      for (int nf = 0; nf < 4; ++nf)
        bf[nf] = *(const f16x8*)(Bs + (wn * 64 + nf * 16 + lr) * 128 + sb);
#pragma unroll
      for (int mf = 0; mf < 4; ++mf)
#pragma unroll
        for (int nf = 0; nf < 4; ++nf)
          acc[mf][nf] = __builtin_amdgcn_mfma_f32_16x16x32_f16(af[mf], bf[nf], acc[mf][nf], 0, 0, 0);
    }
  }

  // epilogue: C/D layout col=lane&15, row=(lane>>4)*4+reg (m89/m91-verified)
#pragma unroll
  for (int mf = 0; mf < 4; ++mf) {
#pragma unroll
    for (int nf = 0; nf < 4; ++nf) {
      const int gcol = n0 + wn * 64 + nf * 16 + lr;
      const float bb = (gcol < 1023) ? bv[gcol] : 0.0f;
#pragma unroll
      for (int r = 0; r < 4; ++r) {
        const int grow = m0 + wm * 64 + mf * 16 + lh * 4 + r;
        const float s = acc[mf][nf][r] + bb;
        const float e = __expf(-s);
        const float pr = 1.0f / (1.0f + e);
        const float qr = pr * e;              // = 1-p with full relative precision
        H2 w; w.h[0] = (_Float16)pr; w.h[1] = (_Float16)qr;
        pq[(size_t)grow * 1024 + gcol] = w.u;
      }
    }
  }
}

// ---- leaf probabilities: lp[s][l] = prod over path of (bit ? p : q) ----
__global__ __launch_bounds__(256) void k_leaf(const uint32_t* __restrict__ pq,
                                              _Float16* __restrict__ lp) {
  const int tid = threadIdx.x;
  const int s = blockIdx.x * 4 + (tid >> 6);
  const int g = tid & 63;                    // depth-6 subtree id
  const uint32_t* pr = pq + (size_t)s * 1024;
  float prob = 1.0f;
  int node = 0;
#pragma unroll
  for (int d = 0; d < 6; ++d) {
    int bit = (g >> (5 - d)) & 1;
    H2 w; w.u = pr[node];
    prob *= (float)(bit ? w.h[0] : w.h[1]);
    node = 2 * node + 1 + bit;
  }
  f16x8 o0, o1;
#pragma unroll
  for (int j = 0; j < 16; ++j) {
    float pp = prob;
    int nd = node;
#pragma unroll
    for (int d = 0; d < 4; ++d) {
      int bit = (j >> (3 - d)) & 1;
      H2 w; w.u = pr[nd];
      pp *= (float)(bit ? w.h[0] : w.h[1]);
      nd = 2 * nd + 1 + bit;
    }
    if (j < 8) o0[j] = (_Float16)pp; else o1[j - 8] = (_Float16)pp;
  }
  *(f16x8*)(lp + (size_t)s * 1024 + g * 16) = o0;
  *(f16x8*)(lp + (size_t)s * 1024 + g * 16 + 8) = o1;
}

// ---- GEMM2: out = lp @ leaf_logits, 64x64 tile, BK=64 ----
__global__ __launch_bounds__(256) void k_gemm2(
    const _Float16* __restrict__ lp,   // [8192][1024]
    const _Float16* __restrict__ LLt,  // [64][1024]
    float* __restrict__ out)           // [8192][64]
{
  __shared__ __align__(16) unsigned char As[8192];
  __shared__ __align__(16) unsigned char Bs[8192];
  const int m0 = blockIdx.x * 64;
  const int tid = threadIdx.x;
  const int wid = tid >> 6, lane = tid & 63;
  const int lr = lane & 15, lh = lane >> 4;

  f32x4 acc[4];
  for (int i = 0; i < 4; ++i) acc[i] = (f32x4)(0.0f);

  const _Float16* srcA[2]; const _Float16* srcB[2];
  unsigned char *dstA[2], *dstB[2];
#pragma unroll
  for (int j = 0; j < 2; ++j) {
    int blk = j * 4 + wid;          // 0..7
    int q = blk * 64 + lane;        // chunk id 0..511
    int i = q >> 3, c = q & 7;
    int cs = c ^ (i & 7);
    srcA[j] = lp + (size_t)(m0 + i) * 1024 + cs * 8;
    srcB[j] = LLt + (size_t)i * 1024 + cs * 8;
    dstA[j] = As + blk * 1024;
    dstB[j] = Bs + blk * 1024;
  }
  const int slot0 = ((0 + lh) ^ (lr & 7)) * 16;
  const int slot1 = ((4 + lh) ^ (lr & 7)) * 16;

  for (int kt = 0; kt < 16; ++kt) {
    __syncthreads();
#pragma unroll
    for (int j = 0; j < 2; ++j) gl_lds16(srcA[j] + kt * 64, dstA[j]);
#pragma unroll
    for (int j = 0; j < 2; ++j) gl_lds16(srcB[j] + kt * 64, dstB[j]);
    __syncthreads();
#pragma unroll
    for (int ph = 0; ph < 2; ++ph) {
      const int sb = ph ? slot1 : slot0;
      f16x8 af = *(const f16x8*)(As + (wid * 16 + lr) * 128 + sb);
#pragma unroll
      for (int nf = 0; nf < 4; ++nf) {
        f16x8 bf = *(const f16x8*)(Bs + (nf * 16 + lr) * 128 + sb);
        acc[nf] = __builtin_amdgcn_mfma_f32_16x16x32_f16(af, bf, acc[nf], 0, 0, 0);
      }
    }
  }
#pragma unroll
  for (int nf = 0; nf < 4; ++nf)
#pragma unroll
    for (int r = 0; r < 4; ++r) {
      int grow = m0 + wid * 16 + lh * 4 + r;
      int gcol = nf * 16 + lr;
      out[(size_t)grow * 64 + gcol] = acc[nf][r];
    }
}

extern "C" void kernel_launch(void* const* d_in, const int* in_sizes, int n_in,
                              void* d_out, int out_size, void* d_ws, size_t ws_size,
                              hipStream_t stream) {
  const float* feat = (const float*)d_in[0];
  const float* W    = (const float*)d_in[1];
  const float* bv   = (const float*)d_in[2];
  const float* LL   = (const float*)d_in[3];
  float* out = (float*)d_out;
  char* ws = (char*)d_ws;

  // ws layout (bytes): fA 16MiB @0 (reused as lp) | Wt 2MiB @16MiB | LLt @18MiB | pq 32MiB @19MiB
  _Float16* fA  = (_Float16*)(ws);
  _Float16* Wt  = (_Float16*)(ws + (size_t)(16u << 20));
  _Float16* LLt = (_Float16*)(ws + (size_t)(18u << 20));
  uint32_t* pq  = (uint32_t*)(ws + (size_t)(19u << 20));
  _Float16* lp  = fA;   // fA dead after gemm1

  k_convf <<<4096, 256, 0, stream>>>(feat, fA);
  k_convw <<<256,  256, 0, stream>>>(W, Wt);
  k_convll<<<64,   256, 0, stream>>>(LL, LLt);
  k_gemm1 <<<512,  256, 0, stream>>>(fA, Wt, bv, pq);
  k_leaf  <<<2048, 256, 0, stream>>>(pq, lp);
  k_gemm2 <<<128,  256, 0, stream>>>(lp, LLt, out);
}

// Round 10
// 133.755 us; speedup vs baseline: 1.0210x; 1.0210x over previous
//
#include <hip/hip_runtime.h>
#include <cstdint>

typedef __attribute__((ext_vector_type(8))) _Float16 f16x8;
typedef __attribute__((ext_vector_type(4))) float f32x4;

union H2 { uint32_t u; _Float16 h[2]; };

__device__ __forceinline__ void gl_lds16(const void* g, void* lds) {
  __builtin_amdgcn_global_load_lds(
      (const __attribute__((address_space(1))) char*)g,
      (__attribute__((address_space(3))) char*)lds,
      16, 0, 0);
}

__device__ __forceinline__ float hp(uint32_t u, int bit) {
  H2 w; w.u = u; return (float)(bit ? w.h[0] : w.h[1]);
}

// ---- features f32 -> f16 ----
__global__ __launch_bounds__(256) void k_convf(const float* __restrict__ in,
                                               _Float16* __restrict__ out) {
  size_t i = ((size_t)blockIdx.x * 256 + threadIdx.x) * 8;
  float4 a = *(const float4*)(in + i);
  float4 b = *(const float4*)(in + i + 4);
  f16x8 o;
  o[0] = (_Float16)a.x; o[1] = (_Float16)a.y; o[2] = (_Float16)a.z; o[3] = (_Float16)a.w;
  o[4] = (_Float16)b.x; o[5] = (_Float16)b.y; o[6] = (_Float16)b.z; o[7] = (_Float16)b.w;
  *(f16x8*)(out + i) = o;
}

// ---- merged: W transpose-convert (blocks 0..255) + leaf_logits transpose (blocks 256..319) ----
__global__ __launch_bounds__(256) void k_convwll(const float* __restrict__ W,
                                                 const float* __restrict__ LL,
                                                 _Float16* __restrict__ Wt,
                                                 _Float16* __restrict__ LLt) {
  __shared__ float tile[64][65];
  int bid = blockIdx.x;
  if (bid < 256) {
    int bx = bid & 15;   // n tile
    int by = bid >> 4;   // k tile
    int n0 = bx * 64, k0 = by * 64;
    int tx = threadIdx.x & 63, ty = threadIdx.x >> 6;
#pragma unroll
    for (int r = 0; r < 16; ++r) {
      int kl = ty * 16 + r;
      int n = n0 + tx;
      tile[kl][tx] = (n < 1023) ? W[(size_t)(k0 + kl) * 1023 + n] : 0.0f;
    }
    __syncthreads();
#pragma unroll
    for (int r = 0; r < 16; ++r) {
      int nl = ty * 16 + r;
      Wt[(size_t)(n0 + nl) * 1024 + k0 + tx] = (_Float16)tile[tx][nl];
    }
  } else {
    int a = bid - 256;
    int t = threadIdx.x;
#pragma unroll
    for (int j = 0; j < 4; ++j) {
      int l = t + j * 256;
      LLt[(size_t)a * 1024 + l] = (_Float16)LL[(size_t)l * 64 + a];
    }
  }
}

// ---- GEMM1: p/q = sigmoid(features @ W + b), packed f16 pair per node ----
// 128x128 tile, BK=64, 4 waves (2x2), 2-phase double-buffered (T3 minimum recipe).
// pq row layout is 1-BASED heap: node n stored at row index n+1 (aligns subtree
// blocks for k_leaf's vector loads); index 0 unused.
__global__ __launch_bounds__(256) void k_gemm1(
    const _Float16* __restrict__ fA,   // [8192][1024]
    const _Float16* __restrict__ Wt,   // [1024][1024]
    const float* __restrict__ bv,      // [1023]
    uint32_t* __restrict__ pq)         // [8192][1024] packed {p,q}, 1-based
{
  __shared__ __align__(16) unsigned char As[32768];   // 2 x 16KB
  __shared__ __align__(16) unsigned char Bs[32768];
  const int bid = blockIdx.x;
  const int id = (bid & 7) * 64 + (bid >> 3);       // XCD swizzle (512 % 8 == 0)
  const int mt = id >> 3, nt = id & 7;
  const int m0 = mt * 128, n0 = nt * 128;
  const int tid = threadIdx.x;
  const int wid = tid >> 6, lane = tid & 63;
  const int wm = wid >> 1, wn = wid & 1;
  const int lr = lane & 15, lh = lane >> 4;

  f32x4 acc[4][4];
  for (int i = 0; i < 4; ++i)
    for (int j = 0; j < 4; ++j)
      acc[i][j] = (f32x4)(0.0f);

  // staging: LDS slot chunk (i, c) holds global chunk (i, c ^ (i&7)); linear LDS dest,
  // inverse-swizzled per-lane global source (rule #21)
  const _Float16* srcA[4]; const _Float16* srcB[4];
  int off[4];
#pragma unroll
  for (int j = 0; j < 4; ++j) {
    int blk = j * 4 + wid;          // 0..15
    int q = blk * 64 + lane;        // chunk id 0..1023
    int i = q >> 3, c = q & 7;
    int cs = c ^ (i & 7);
    srcA[j] = fA + (size_t)(m0 + i) * 1024 + cs * 8;
    srcB[j] = Wt + (size_t)(n0 + i) * 1024 + cs * 8;
    off[j] = blk * 1024;
  }
  const int slot0 = ((0 + lh) ^ (lr & 7)) * 16;   // (row&7) == (lr&7)
  const int slot1 = ((4 + lh) ^ (lr & 7)) * 16;

  // prologue: stage tile 0 into buffer 0
#pragma unroll
  for (int j = 0; j < 4; ++j) gl_lds16(srcA[j], As + off[j]);
#pragma unroll
  for (int j = 0; j < 4; ++j) gl_lds16(srcB[j], Bs + off[j]);
  __syncthreads();                                  // drains vmcnt

  int cb = 0;                                       // current buffer byte offset
  for (int kt = 0; kt < 16; ++kt) {
    if (kt < 15) {                                  // issue next-tile loads first
      const int nb = cb ^ 16384;
#pragma unroll
      for (int j = 0; j < 4; ++j) gl_lds16(srcA[j] + (kt + 1) * 64, As + nb + off[j]);
#pragma unroll
      for (int j = 0; j < 4; ++j) gl_lds16(srcB[j] + (kt + 1) * 64, Bs + nb + off[j]);
    }
    __builtin_amdgcn_s_setprio(1);
#pragma unroll
    for (int ph = 0; ph < 2; ++ph) {
      const int sb = (ph ? slot1 : slot0) + cb;
      f16x8 af[4], bf[4];
#pragma unroll
      for (int mf = 0; mf < 4; ++mf)
        af[mf] = *(const f16x8*)(As + (wm * 64 + mf * 16 + lr) * 128 + sb);
#pragma unroll
      for (int nf = 0; nf < 4; ++nf)
        bf[nf] = *(const f16x8*)(Bs + (wn * 64 + nf * 16 + lr) * 128 + sb);
#pragma unroll
      for (int mf = 0; mf < 4; ++mf)
#pragma unroll
        for (int nf = 0; nf < 4; ++nf)
          acc[mf][nf] = __builtin_amdgcn_mfma_f32_16x16x32_f16(af[mf], bf[nf], acc[mf][nf], 0, 0, 0);
    }
    __builtin_amdgcn_s_setprio(0);
    __syncthreads();                                // drains prefetch vmcnt (hidden under MFMA)
    cb ^= 16384;
  }

  // epilogue: C/D layout col=lane&15, row=(lane>>4)*4+reg (m89/m91-verified)
  // store node gcol at 1-based index gcol+1 (pad col 1023 wraps to unused slot 0)
#pragma unroll
  for (int mf = 0; mf < 4; ++mf) {
#pragma unroll
    for (int nf = 0; nf < 4; ++nf) {
      const int gcol = n0 + wn * 64 + nf * 16 + lr;
      const float bb = (gcol < 1023) ? bv[gcol] : 0.0f;
      const int idx = (gcol + 1) & 1023;
#pragma unroll
      for (int r = 0; r < 4; ++r) {
        const int grow = m0 + wm * 64 + mf * 16 + lh * 4 + r;
        const float s = acc[mf][nf][r] + bb;
        const float e = __expf(-s);
        const float pr = 1.0f / (1.0f + e);
        const float qr = pr * e;              // = 1-p with full relative precision
        H2 w; w.h[0] = (_Float16)pr; w.h[1] = (_Float16)qr;
        pq[(size_t)grow * 1024 + idx] = w.u;
      }
    }
  }
}

// ---- leaf probabilities: lp[s][l] = prod over path of (bit ? p : q) ----
// 1-based heap: depth-d block starts at index 2^d -> lane g's depth-7/8/9
// subtree nodes are ALIGNED vector loads (uint2/uint4/2xuint4). 11 loads/lane.
__global__ __launch_bounds__(256) void k_leaf(const uint32_t* __restrict__ pq,
                                              _Float16* __restrict__ lp) {
  const int tid = threadIdx.x;
  const int s = blockIdx.x * 4 + (tid >> 6);
  const int g = tid & 63;                    // owns leaves g*16 .. g*16+15
  const uint32_t* pr = pq + (size_t)s * 1024;

  // prefix: depths 0..5 (bits from g), 1-based walk: child = 2*node + bit
  float P = 1.0f;
  int node = 1;
#pragma unroll
  for (int d = 0; d < 6; ++d) {
    int bit = (g >> (5 - d)) & 1;
    P *= hp(pr[node], bit);
    node = 2 * node + bit;                   // ends at 64+g
  }

  // subtree loads (aligned in 1-based layout)
  const uint32_t u6 = pr[64 + g];
  const uint2 u7 = *(const uint2*)(pr + 128 + 2 * g);
  const uint4 u8 = *(const uint4*)(pr + 256 + 4 * g);
  const uint4 u9a = *(const uint4*)(pr + 512 + 8 * g);
  const uint4 u9b = *(const uint4*)(pr + 512 + 8 * g + 4);

  // c67[b6][b7] = P * f6(b6) * f7(b6,b7)
  float c67[2][2];
#pragma unroll
  for (int b6 = 0; b6 < 2; ++b6) {
    const float f6 = hp(u6, b6);
    const uint32_t w7 = b6 ? u7.y : u7.x;
#pragma unroll
    for (int b7 = 0; b7 < 2; ++b7)
      c67[b6][b7] = P * f6 * hp(w7, b7);
  }
  const uint32_t u8a[4] = {u8.x, u8.y, u8.z, u8.w};
  float f8[4][2];
#pragma unroll
  for (int m = 0; m < 4; ++m) { f8[m][0] = hp(u8a[m], 0); f8[m][1] = hp(u8a[m], 1); }
  const uint32_t u9[8] = {u9a.x, u9a.y, u9a.z, u9a.w, u9b.x, u9b.y, u9b.z, u9b.w};
  float f9[8][2];
#pragma unroll
  for (int m = 0; m < 8; ++m) { f9[m][0] = hp(u9[m], 0); f9[m][1] = hp(u9[m], 1); }

  f16x8 o0, o1;
#pragma unroll
  for (int j = 0; j < 16; ++j) {
    float v = c67[j >> 3][(j >> 2) & 1] * f8[j >> 2][(j >> 1) & 1] * f9[j >> 1][j & 1];
    if (j < 8) o0[j] = (_Float16)v; else o1[j - 8] = (_Float16)v;
  }
  *(f16x8*)(lp + (size_t)s * 1024 + g * 16) = o0;
  *(f16x8*)(lp + (size_t)s * 1024 + g * 16 + 8) = o1;
}

// ---- GEMM2: out = lp @ leaf_logits, 64x64 tile, BK=64 ----
__global__ __launch_bounds__(256) void k_gemm2(
    const _Float16* __restrict__ lp,   // [8192][1024]
    const _Float16* __restrict__ LLt,  // [64][1024]
    float* __restrict__ out)           // [8192][64]
{
  __shared__ __align__(16) unsigned char As[8192];
  __shared__ __align__(16) unsigned char Bs[8192];
  const int m0 = blockIdx.x * 64;
  const int tid = threadIdx.x;
  const int wid = tid >> 6, lane = tid & 63;
  const int lr = lane & 15, lh = lane >> 4;

  f32x4 acc[4];
  for (int i = 0; i < 4; ++i) acc[i] = (f32x4)(0.0f);

  const _Float16* srcA[2]; const _Float16* srcB[2];
  unsigned char *dstA[2], *dstB[2];
#pragma unroll
  for (int j = 0; j < 2; ++j) {
    int blk = j * 4 + wid;          // 0..7
    int q = blk * 64 + lane;        // chunk id 0..511
    int i = q >> 3, c = q & 7;
    int cs = c ^ (i & 7);
    srcA[j] = lp + (size_t)(m0 + i) * 1024 + cs * 8;
    srcB[j] = LLt + (size_t)i * 1024 + cs * 8;
    dstA[j] = As + blk * 1024;
    dstB[j] = Bs + blk * 1024;
  }
  const int slot0 = ((0 + lh) ^ (lr & 7)) * 16;
  const int slot1 = ((4 + lh) ^ (lr & 7)) * 16;

  for (int kt = 0; kt < 16; ++kt) {
    __syncthreads();
#pragma unroll
    for (int j = 0; j < 2; ++j) gl_lds16(srcA[j] + kt * 64, dstA[j]);
#pragma unroll
    for (int j = 0; j < 2; ++j) gl_lds16(srcB[j] + kt * 64, dstB[j]);
    __syncthreads();
#pragma unroll
    for (int ph = 0; ph < 2; ++ph) {
      const int sb = ph ? slot1 : slot0;
      f16x8 af = *(const f16x8*)(As + (wid * 16 + lr) * 128 + sb);
#pragma unroll
      for (int nf = 0; nf < 4; ++nf) {
        f16x8 bf = *(const f16x8*)(Bs + (nf * 16 + lr) * 128 + sb);
        acc[nf] = __builtin_amdgcn_mfma_f32_16x16x32_f16(af, bf, acc[nf], 0, 0, 0);
      }
    }
  }
#pragma unroll
  for (int nf = 0; nf < 4; ++nf)
#pragma unroll
    for (int r = 0; r < 4; ++r) {
      int grow = m0 + wid * 16 + lh * 4 + r;
      int gcol = nf * 16 + lr;
      out[(size_t)grow * 64 + gcol] = acc[nf][r];
    }
}

extern "C" void kernel_launch(void* const* d_in, const int* in_sizes, int n_in,
                              void* d_out, int out_size, void* d_ws, size_t ws_size,
                              hipStream_t stream) {
  const float* feat = (const float*)d_in[0];
  const float* W    = (const float*)d_in[1];
  const float* bv   = (const float*)d_in[2];
  const float* LL   = (const float*)d_in[3];
  float* out = (float*)d_out;
  char* ws = (char*)d_ws;

  // ws layout (bytes): fA 16MiB @0 (reused as lp) | Wt 2MiB @16MiB | LLt @18MiB | pq 32MiB @19MiB
  _Float16* fA  = (_Float16*)(ws);
  _Float16* Wt  = (_Float16*)(ws + (size_t)(16u << 20));
  _Float16* LLt = (_Float16*)(ws + (size_t)(18u << 20));
  uint32_t* pq  = (uint32_t*)(ws + (size_t)(19u << 20));
  _Float16* lp  = fA;   // fA dead after gemm1

  k_convf  <<<4096, 256, 0, stream>>>(feat, fA);
  k_convwll<<<320,  256, 0, stream>>>(W, LL, Wt, LLt);
  k_gemm1  <<<512,  256, 0, stream>>>(fA, Wt, bv, pq);
  k_leaf   <<<2048, 256, 0, stream>>>(pq, lp);
  k_gemm2  <<<128,  256, 0, stream>>>(lp, LLt, out);
}

// Round 11
// 124.701 us; speedup vs baseline: 1.0951x; 1.0726x over previous
//
#include <hip/hip_runtime.h>
#include <cstdint>

typedef __attribute__((ext_vector_type(8))) _Float16 f16x8;
typedef __attribute__((ext_vector_type(4))) float f32x4;

union H2 { uint32_t u; _Float16 h[2]; };

__device__ __forceinline__ void gl_lds16(const void* g, void* lds) {
  __builtin_amdgcn_global_load_lds(
      (const __attribute__((address_space(1))) char*)g,
      (__attribute__((address_space(3))) char*)lds,
      16, 0, 0);
}

__device__ __forceinline__ float hp(uint32_t u, int bit) {
  H2 w; w.u = u; return (float)(bit ? w.h[0] : w.h[1]);
}

// ---- merged prep: features f32->f16 (bid<4096) | W transpose (4096..4351) | LL transpose (4352..4415) ----
__global__ __launch_bounds__(256) void k_prep(const float* __restrict__ in,
                                              const float* __restrict__ W,
                                              const float* __restrict__ LL,
                                              _Float16* __restrict__ fA,
                                              _Float16* __restrict__ Wt,
                                              _Float16* __restrict__ LLt) {
  __shared__ float tile[64][65];
  const int bid = blockIdx.x;
  if (bid < 4096) {
    size_t i = ((size_t)bid * 256 + threadIdx.x) * 8;
    float4 a = *(const float4*)(in + i);
    float4 b = *(const float4*)(in + i + 4);
    f16x8 o;
    o[0] = (_Float16)a.x; o[1] = (_Float16)a.y; o[2] = (_Float16)a.z; o[3] = (_Float16)a.w;
    o[4] = (_Float16)b.x; o[5] = (_Float16)b.y; o[6] = (_Float16)b.z; o[7] = (_Float16)b.w;
    *(f16x8*)(fA + i) = o;
  } else if (bid < 4352) {
    int b = bid - 4096;
    int bx = b & 15;   // n tile
    int by = b >> 4;   // k tile
    int n0 = bx * 64, k0 = by * 64;
    int tx = threadIdx.x & 63, ty = threadIdx.x >> 6;
#pragma unroll
    for (int r = 0; r < 16; ++r) {
      int kl = ty * 16 + r;
      int n = n0 + tx;
      tile[kl][tx] = (n < 1023) ? W[(size_t)(k0 + kl) * 1023 + n] : 0.0f;
    }
    __syncthreads();
#pragma unroll
    for (int r = 0; r < 16; ++r) {
      int nl = ty * 16 + r;
      Wt[(size_t)(n0 + nl) * 1024 + k0 + tx] = (_Float16)tile[tx][nl];
    }
  } else {
    int a = bid - 4352;
    int t = threadIdx.x;
#pragma unroll
    for (int j = 0; j < 4; ++j) {
      int l = t + j * 256;
      LLt[(size_t)a * 1024 + l] = (_Float16)LL[(size_t)l * 64 + a];
    }
  }
}

// ---- GEMM1: p/q = sigmoid(features @ W + b), packed f16 pair per node ----
// unchanged from R10 (passed): 128x128, BK=64, 2-phase dbuf, 1-based heap output
__global__ __launch_bounds__(256) void k_gemm1(
    const _Float16* __restrict__ fA,   // [8192][1024]
    const _Float16* __restrict__ Wt,   // [1024][1024]
    const float* __restrict__ bv,      // [1023]
    uint32_t* __restrict__ pq)         // [8192][1024] packed {p,q}, 1-based
{
  __shared__ __align__(16) unsigned char As[32768];   // 2 x 16KB
  __shared__ __align__(16) unsigned char Bs[32768];
  const int bid = blockIdx.x;
  const int id = (bid & 7) * 64 + (bid >> 3);       // XCD swizzle (512 % 8 == 0)
  const int mt = id >> 3, nt = id & 7;
  const int m0 = mt * 128, n0 = nt * 128;
  const int tid = threadIdx.x;
  const int wid = tid >> 6, lane = tid & 63;
  const int wm = wid >> 1, wn = wid & 1;
  const int lr = lane & 15, lh = lane >> 4;

  f32x4 acc[4][4];
  for (int i = 0; i < 4; ++i)
    for (int j = 0; j < 4; ++j)
      acc[i][j] = (f32x4)(0.0f);

  const _Float16* srcA[4]; const _Float16* srcB[4];
  int off[4];
#pragma unroll
  for (int j = 0; j < 4; ++j) {
    int blk = j * 4 + wid;          // 0..15
    int q = blk * 64 + lane;        // chunk id 0..1023
    int i = q >> 3, c = q & 7;
    int cs = c ^ (i & 7);
    srcA[j] = fA + (size_t)(m0 + i) * 1024 + cs * 8;
    srcB[j] = Wt + (size_t)(n0 + i) * 1024 + cs * 8;
    off[j] = blk * 1024;
  }
  const int slot0 = ((0 + lh) ^ (lr & 7)) * 16;   // (row&7) == (lr&7)
  const int slot1 = ((4 + lh) ^ (lr & 7)) * 16;

#pragma unroll
  for (int j = 0; j < 4; ++j) gl_lds16(srcA[j], As + off[j]);
#pragma unroll
  for (int j = 0; j < 4; ++j) gl_lds16(srcB[j], Bs + off[j]);
  __syncthreads();

  int cb = 0;
  for (int kt = 0; kt < 16; ++kt) {
    if (kt < 15) {
      const int nb = cb ^ 16384;
#pragma unroll
      for (int j = 0; j < 4; ++j) gl_lds16(srcA[j] + (kt + 1) * 64, As + nb + off[j]);
#pragma unroll
      for (int j = 0; j < 4; ++j) gl_lds16(srcB[j] + (kt + 1) * 64, Bs + nb + off[j]);
    }
    __builtin_amdgcn_s_setprio(1);
#pragma unroll
    for (int ph = 0; ph < 2; ++ph) {
      const int sb = (ph ? slot1 : slot0) + cb;
      f16x8 af[4], bf[4];
#pragma unroll
      for (int mf = 0; mf < 4; ++mf)
        af[mf] = *(const f16x8*)(As + (wm * 64 + mf * 16 + lr) * 128 + sb);
#pragma unroll
      for (int nf = 0; nf < 4; ++nf)
        bf[nf] = *(const f16x8*)(Bs + (wn * 64 + nf * 16 + lr) * 128 + sb);
#pragma unroll
      for (int mf = 0; mf < 4; ++mf)
#pragma unroll
        for (int nf = 0; nf < 4; ++nf)
          acc[mf][nf] = __builtin_amdgcn_mfma_f32_16x16x32_f16(af[mf], bf[nf], acc[mf][nf], 0, 0, 0);
    }
    __builtin_amdgcn_s_setprio(0);
    __syncthreads();
    cb ^= 16384;
  }

#pragma unroll
  for (int mf = 0; mf < 4; ++mf) {
#pragma unroll
    for (int nf = 0; nf < 4; ++nf) {
      const int gcol = n0 + wn * 64 + nf * 16 + lr;
      const float bb = (gcol < 1023) ? bv[gcol] : 0.0f;
      const int idx = (gcol + 1) & 1023;
#pragma unroll
      for (int r = 0; r < 4; ++r) {
        const int grow = m0 + wm * 64 + mf * 16 + lh * 4 + r;
        const float s = acc[mf][nf][r] + bb;
        const float e = __expf(-s);
        const float pr = 1.0f / (1.0f + e);
        const float qr = pr * e;
        H2 w; w.h[0] = (_Float16)pr; w.h[1] = (_Float16)qr;
        pq[(size_t)grow * 1024 + idx] = w.u;
      }
    }
  }
}

// ---- fused leaf + GEMM2: per block, 16 samples ----
// phase 1: leaf probs (1-based heap, aligned vector loads) -> LP in LDS,
//          written at XOR-swizzled chunks ((c&7)^(row&7)) so phase-2 ds_reads
//          are conflict-reduced (same key as read; both-sides rule #21)
// phase 2: out[16][64] = LP @ LLt^T, B double-buffered via global_load_lds
__global__ __launch_bounds__(256) void k_out(
    const uint32_t* __restrict__ pq,   // [8192][1024] 1-based rows
    const _Float16* __restrict__ LLt,  // [64][1024]
    float* __restrict__ out)           // [8192][64]
{
  __shared__ __align__(16) unsigned char LP[32768];   // 16 rows x 2048 B
  __shared__ __align__(16) unsigned char Bs[16384];   // 2 x 8 KB
  const int m0 = blockIdx.x * 16;
  const int tid = threadIdx.x;
  const int wid = tid >> 6, lane = tid & 63;
  const int lr = lane & 15, lh = lane >> 4;

  // ---- phase 1 ----
#pragma unroll
  for (int r4 = 0; r4 < 4; ++r4) {
    const int sl = r4 * 4 + wid;        // 0..15
    const int g = lane;                 // 0..63, owns leaves g*16..g*16+15
    const uint32_t* pr = pq + (size_t)(m0 + sl) * 1024;

    float P = 1.0f;
    int node = 1;
#pragma unroll
    for (int d = 0; d < 6; ++d) {
      int bit = (g >> (5 - d)) & 1;
      P *= hp(pr[node], bit);
      node = 2 * node + bit;
    }
    const uint32_t u6 = pr[64 + g];
    const uint2 u7 = *(const uint2*)(pr + 128 + 2 * g);
    const uint4 u8 = *(const uint4*)(pr + 256 + 4 * g);
    const uint4 u9a = *(const uint4*)(pr + 512 + 8 * g);
    const uint4 u9b = *(const uint4*)(pr + 512 + 8 * g + 4);

    float c67[2][2];
#pragma unroll
    for (int b6 = 0; b6 < 2; ++b6) {
      const float f6 = hp(u6, b6);
      const uint32_t w7 = b6 ? u7.y : u7.x;
#pragma unroll
      for (int b7 = 0; b7 < 2; ++b7)
        c67[b6][b7] = P * f6 * hp(w7, b7);
    }
    const uint32_t u8a[4] = {u8.x, u8.y, u8.z, u8.w};
    float f8[4][2];
#pragma unroll
    for (int m = 0; m < 4; ++m) { f8[m][0] = hp(u8a[m], 0); f8[m][1] = hp(u8a[m], 1); }
    const uint32_t u9[8] = {u9a.x, u9a.y, u9a.z, u9a.w, u9b.x, u9b.y, u9b.z, u9b.w};
    float f9[8][2];
#pragma unroll
    for (int m = 0; m < 8; ++m) { f9[m][0] = hp(u9[m], 0); f9[m][1] = hp(u9[m], 1); }

    f16x8 o0, o1;
#pragma unroll
    for (int j = 0; j < 16; ++j) {
      float v = c67[j >> 3][(j >> 2) & 1] * f8[j >> 2][(j >> 1) & 1] * f9[j >> 1][j & 1];
      if (j < 8) o0[j] = (_Float16)v; else o1[j - 8] = (_Float16)v;
    }
    // chunks 2g, 2g+1 (16B each) at swizzled in-group position
    const int key = sl & 7;
    const int c0 = 2 * g, c1 = 2 * g + 1;
    *(f16x8*)(LP + sl * 2048 + ((c0 & ~7) | ((c0 & 7) ^ key)) * 16) = o0;
    *(f16x8*)(LP + sl * 2048 + ((c1 & ~7) | ((c1 & 7) ^ key)) * 16) = o1;
  }

  // ---- phase 2 ----
  const _Float16* srcB[2];
  int offB[2];
#pragma unroll
  for (int j = 0; j < 2; ++j) {
    int blk = j * 4 + wid;          // 0..7
    int q = blk * 64 + lane;        // 0..511
    int i = q >> 3, c = q & 7;      // i = action row 0..63
    srcB[j] = LLt + (size_t)i * 1024 + (c ^ (i & 7)) * 8;
    offB[j] = blk * 1024;
  }
#pragma unroll
  for (int j = 0; j < 2; ++j) gl_lds16(srcB[j], Bs + offB[j]);
  __syncthreads();   // joins phase 1 + drains B stage

  f32x4 acc = (f32x4)(0.0f);
  int cb = 0;
  for (int kt = 0; kt < 16; ++kt) {
    if (kt < 15) {
      const int nb = cb ^ 8192;
#pragma unroll
      for (int j = 0; j < 2; ++j) gl_lds16(srcB[j] + (kt + 1) * 64, Bs + nb + offB[j]);
    }
#pragma unroll
    for (int ph = 0; ph < 2; ++ph) {
      const int sc = ((ph * 4 + lh) ^ (lr & 7)) * 16;
      f16x8 af = *(const f16x8*)(LP + lr * 2048 + kt * 128 + sc);
      f16x8 bf = *(const f16x8*)(Bs + cb + (wid * 16 + lr) * 128 + sc);
      acc = __builtin_amdgcn_mfma_f32_16x16x32_f16(af, bf, acc, 0, 0, 0);
    }
    __syncthreads();
    cb ^= 8192;
  }
  // C/D: col=lane&15, row=lh*4+reg
#pragma unroll
  for (int r = 0; r < 4; ++r)
    out[(size_t)(m0 + lh * 4 + r) * 64 + wid * 16 + lr] = acc[r];
}

extern "C" void kernel_launch(void* const* d_in, const int* in_sizes, int n_in,
                              void* d_out, int out_size, void* d_ws, size_t ws_size,
                              hipStream_t stream) {
  const float* feat = (const float*)d_in[0];
  const float* W    = (const float*)d_in[1];
  const float* bv   = (const float*)d_in[2];
  const float* LL   = (const float*)d_in[3];
  float* out = (float*)d_out;
  char* ws = (char*)d_ws;

  // ws layout (bytes): fA 16MiB @0 | Wt 2MiB @16MiB | LLt @18MiB | pq 32MiB @19MiB
  _Float16* fA  = (_Float16*)(ws);
  _Float16* Wt  = (_Float16*)(ws + (size_t)(16u << 20));
  _Float16* LLt = (_Float16*)(ws + (size_t)(18u << 20));
  uint32_t* pq  = (uint32_t*)(ws + (size_t)(19u << 20));

  k_prep <<<4416, 256, 0, stream>>>(feat, W, LL, fA, Wt, LLt);
  k_gemm1<<<512,  256, 0, stream>>>(fA, Wt, bv, pq);
  k_out  <<<512,  256, 0, stream>>>(pq, LLt, out);
}

// Round 13
// 123.112 us; speedup vs baseline: 1.1092x; 1.0129x over previous
//
#include <hip/hip_runtime.h>
#include <cstdint>

typedef __attribute__((ext_vector_type(8))) _Float16 f16x8;
typedef __attribute__((ext_vector_type(4))) float f32x4;

union H2 { uint32_t u; _Float16 h[2]; };

__device__ __forceinline__ void gl_lds16(const void* g, void* lds) {
  __builtin_amdgcn_global_load_lds(
      (const __attribute__((address_space(1))) char*)g,
      (__attribute__((address_space(3))) char*)lds,
      16, 0, 0);
}

__device__ __forceinline__ float hp(uint32_t u, int bit) {
  H2 w; w.u = u; return (float)(bit ? w.h[0] : w.h[1]);
}

// ---- merged prep: features f32->f16 (bid<4096) | W transpose (4096..4351) | LL transpose (4352..4415) ----
__global__ __launch_bounds__(256) void k_prep(const float* __restrict__ in,
                                              const float* __restrict__ W,
                                              const float* __restrict__ LL,
                                              _Float16* __restrict__ fA,
                                              _Float16* __restrict__ Wt,
                                              _Float16* __restrict__ LLt) {
  __shared__ float tile[64][65];
  const int bid = blockIdx.x;
  if (bid < 4096) {
    size_t i = ((size_t)bid * 256 + threadIdx.x) * 8;
    float4 a = *(const float4*)(in + i);
    float4 b = *(const float4*)(in + i + 4);
    f16x8 o;
    o[0] = (_Float16)a.x; o[1] = (_Float16)a.y; o[2] = (_Float16)a.z; o[3] = (_Float16)a.w;
    o[4] = (_Float16)b.x; o[5] = (_Float16)b.y; o[6] = (_Float16)b.z; o[7] = (_Float16)b.w;
    *(f16x8*)(fA + i) = o;
  } else if (bid < 4352) {
    int b = bid - 4096;
    int bx = b & 15;   // n tile
    int by = b >> 4;   // k tile
    int n0 = bx * 64, k0 = by * 64;
    int tx = threadIdx.x & 63, ty = threadIdx.x >> 6;
#pragma unroll
    for (int r = 0; r < 16; ++r) {
      int kl = ty * 16 + r;
      int n = n0 + tx;
      tile[kl][tx] = (n < 1023) ? W[(size_t)(k0 + kl) * 1023 + n] : 0.0f;
    }
    __syncthreads();
#pragma unroll
    for (int r = 0; r < 16; ++r) {
      int nl = ty * 16 + r;
      Wt[(size_t)(n0 + nl) * 1024 + k0 + tx] = (_Float16)tile[tx][nl];
    }
  } else {
    int a = bid - 4352;
    int t = threadIdx.x;
#pragma unroll
    for (int j = 0; j < 4; ++j) {
      int l = t + j * 256;
      LLt[(size_t)a * 1024 + l] = (_Float16)LL[(size_t)l * 64 + a];
    }
  }
}

// ---- GEMM1: p/q = sigmoid(features @ W + b), packed f16 pair per node ----
// 128x128, BK=64, 4 waves, COUNTED-VMCNT two-barrier schedule (T4/m218):
//   per iter: issue next tile (8 gl_lds) -> vmcnt(8) [oldest 8 = current tile done,
//   new 8 stay in flight] -> raw s_barrier -> MFMA -> raw s_barrier (WAR guard).
// Output pq: 1-based heap rows (node n at idx n+1).
__global__ __launch_bounds__(256) void k_gemm1(
    const _Float16* __restrict__ fA,   // [8192][1024]
    const _Float16* __restrict__ Wt,   // [1024][1024]
    const float* __restrict__ bv,      // [1023]
    uint32_t* __restrict__ pq)         // [8192][1024] packed {p,q}, 1-based
{
  __shared__ __align__(16) unsigned char As[32768];   // 2 x 16KB
  __shared__ __align__(16) unsigned char Bs[32768];
  const int bid = blockIdx.x;
  const int id = (bid & 7) * 64 + (bid >> 3);       // XCD swizzle (512 % 8 == 0)
  const int mt = id >> 3, nt = id & 7;
  const int m0 = mt * 128, n0 = nt * 128;
  const int tid = threadIdx.x;
  const int wid = tid >> 6, lane = tid & 63;
  const int wm = wid >> 1, wn = wid & 1;
  const int lr = lane & 15, lh = lane >> 4;

  f32x4 acc[4][4];
  for (int i = 0; i < 4; ++i)
    for (int j = 0; j < 4; ++j)
      acc[i][j] = (f32x4)(0.0f);

  const _Float16* srcA[4]; const _Float16* srcB[4];
  int off[4];
#pragma unroll
  for (int j = 0; j < 4; ++j) {
    int blk = j * 4 + wid;          // 0..15
    int q = blk * 64 + lane;        // chunk id 0..1023
    int i = q >> 3, c = q & 7;
    int cs = c ^ (i & 7);
    srcA[j] = fA + (size_t)(m0 + i) * 1024 + cs * 8;
    srcB[j] = Wt + (size_t)(n0 + i) * 1024 + cs * 8;
    off[j] = blk * 1024;
  }
  const int slot0 = ((0 + lh) ^ (lr & 7)) * 16;   // (row&7) == (lr&7)
  const int slot1 = ((4 + lh) ^ (lr & 7)) * 16;

  auto mfma_phase = [&](int cb) {
    __builtin_amdgcn_s_setprio(1);
#pragma unroll
    for (int ph = 0; ph < 2; ++ph) {
      const int sb = (ph ? slot1 : slot0) + cb;
      f16x8 af[4], bf[4];
#pragma unroll
      for (int mf = 0; mf < 4; ++mf)
        af[mf] = *(const f16x8*)(As + (wm * 64 + mf * 16 + lr) * 128 + sb);
#pragma unroll
      for (int nf = 0; nf < 4; ++nf)
        bf[nf] = *(const f16x8*)(Bs + (wn * 64 + nf * 16 + lr) * 128 + sb);
#pragma unroll
      for (int mf = 0; mf < 4; ++mf)
#pragma unroll
        for (int nf = 0; nf < 4; ++nf)
          acc[mf][nf] = __builtin_amdgcn_mfma_f32_16x16x32_f16(af[mf], bf[nf], acc[mf][nf], 0, 0, 0);
    }
    __builtin_amdgcn_s_setprio(0);
  };

  // prologue: issue tile 0 into buffer 0 (no wait yet)
#pragma unroll
  for (int j = 0; j < 4; ++j) gl_lds16(srcA[j], As + off[j]);
#pragma unroll
  for (int j = 0; j < 4; ++j) gl_lds16(srcB[j], Bs + off[j]);

  int cb = 0;
  for (int kt = 0; kt < 15; ++kt) {
    const int nb = cb ^ 16384;
    // issue tile kt+1 (nb's old contents fully read: end-of-iter barrier)
#pragma unroll
    for (int j = 0; j < 4; ++j) gl_lds16(srcA[j] + (kt + 1) * 64, As + nb + off[j]);
#pragma unroll
    for (int j = 0; j < 4; ++j) gl_lds16(srcB[j] + (kt + 1) * 64, Bs + nb + off[j]);
    asm volatile("s_waitcnt vmcnt(8)" ::: "memory");   // oldest 8 (tile kt) done
    __builtin_amdgcn_s_barrier();
    __builtin_amdgcn_sched_barrier(0);
    mfma_phase(cb);
    __builtin_amdgcn_sched_barrier(0);
    __builtin_amdgcn_s_barrier();                      // WAR guard, no drain
    __builtin_amdgcn_sched_barrier(0);
    cb = nb;
  }
  // peeled last tile
  asm volatile("s_waitcnt vmcnt(0)" ::: "memory");
  __builtin_amdgcn_s_barrier();
  __builtin_amdgcn_sched_barrier(0);
  mfma_phase(cb);

  // epilogue: C/D col=lane&15, row=(lane>>4)*4+reg; node gcol -> 1-based idx
#pragma unroll
  for (int mf = 0; mf < 4; ++mf) {
#pragma unroll
    for (int nf = 0; nf < 4; ++nf) {
      const int gcol = n0 + wn * 64 + nf * 16 + lr;
      const float bb = (gcol < 1023) ? bv[gcol] : 0.0f;
      const int idx = (gcol + 1) & 1023;
#pragma unroll
      for (int r = 0; r < 4; ++r) {
        const int grow = m0 + wm * 64 + mf * 16 + lh * 4 + r;
        const float s = acc[mf][nf][r] + bb;
        const float e = __expf(-s);
        const float pr = 1.0f / (1.0f + e);
        const float qr = pr * e;
        H2 w; w.h[0] = (_Float16)pr; w.h[1] = (_Float16)qr;
        pq[(size_t)grow * 1024 + idx] = w.u;
      }
    }
  }
}

// ---- fused leaf + GEMM2, counted-vmcnt B pipeline ----
__global__ __launch_bounds__(256) void k_out(
    const uint32_t* __restrict__ pq,   // [8192][1024] 1-based rows
    const _Float16* __restrict__ LLt,  // [64][1024]
    float* __restrict__ out)           // [8192][64]
{
  __shared__ __align__(16) unsigned char LP[32768];   // 16 rows x 2048 B
  __shared__ __align__(16) unsigned char Bs[16384];   // 2 x 8 KB
  const int m0 = blockIdx.x * 16;
  const int tid = threadIdx.x;
  const int wid = tid >> 6, lane = tid & 63;
  const int lr = lane & 15, lh = lane >> 4;

  // ---- phase 1: leaf probs -> LP (swizzled chunks, key = row&7) ----
#pragma unroll
  for (int r4 = 0; r4 < 4; ++r4) {
    const int sl = r4 * 4 + wid;        // 0..15
    const int g = lane;
    const uint32_t* pr = pq + (size_t)(m0 + sl) * 1024;

    float P = 1.0f;
    int node = 1;
#pragma unroll
    for (int d = 0; d < 6; ++d) {
      int bit = (g >> (5 - d)) & 1;
      P *= hp(pr[node], bit);
      node = 2 * node + bit;
    }
    const uint32_t u6 = pr[64 + g];
    const uint2 u7 = *(const uint2*)(pr + 128 + 2 * g);
    const uint4 u8 = *(const uint4*)(pr + 256 + 4 * g);
    const uint4 u9a = *(const uint4*)(pr + 512 + 8 * g);
    const uint4 u9b = *(const uint4*)(pr + 512 + 8 * g + 4);

    float c67[2][2];
#pragma unroll
    for (int b6 = 0; b6 < 2; ++b6) {
      const float f6 = hp(u6, b6);
      const uint32_t w7 = b6 ? u7.y : u7.x;
#pragma unroll
      for (int b7 = 0; b7 < 2; ++b7)
        c67[b6][b7] = P * f6 * hp(w7, b7);
    }
    const uint32_t u8a[4] = {u8.x, u8.y, u8.z, u8.w};
    float f8[4][2];
#pragma unroll
    for (int m = 0; m < 4; ++m) { f8[m][0] = hp(u8a[m], 0); f8[m][1] = hp(u8a[m], 1); }
    const uint32_t u9[8] = {u9a.x, u9a.y, u9a.z, u9a.w, u9b.x, u9b.y, u9b.z, u9b.w};
    float f9[8][2];
#pragma unroll
    for (int m = 0; m < 8; ++m) { f9[m][0] = hp(u9[m], 0); f9[m][1] = hp(u9[m], 1); }

    f16x8 o0, o1;
#pragma unroll
    for (int j = 0; j < 16; ++j) {
      float v = c67[j >> 3][(j >> 2) & 1] * f8[j >> 2][(j >> 1) & 1] * f9[j >> 1][j & 1];
      if (j < 8) o0[j] = (_Float16)v; else o1[j - 8] = (_Float16)v;
    }
    const int key = sl & 7;
    const int c0 = 2 * g, c1 = 2 * g + 1;
    *(f16x8*)(LP + sl * 2048 + ((c0 & ~7) | ((c0 & 7) ^ key)) * 16) = o0;
    *(f16x8*)(LP + sl * 2048 + ((c1 & ~7) | ((c1 & 7) ^ key)) * 16) = o1;
  }

  // ---- phase 2 ----
  const _Float16* srcB[2];
  int offB[2];
#pragma unroll
  for (int j = 0; j < 2; ++j) {
    int blk = j * 4 + wid;          // 0..7
    int q = blk * 64 + lane;        // 0..511
    int i = q >> 3, c = q & 7;      // i = action row 0..63
    srcB[j] = LLt + (size_t)i * 1024 + (c ^ (i & 7)) * 8;
    offB[j] = blk * 1024;
  }
#pragma unroll
  for (int j = 0; j < 2; ++j) gl_lds16(srcB[j], Bs + offB[j]);
  __syncthreads();   // joins phase 1 LP writes + drains B tile0

  f32x4 acc = (f32x4)(0.0f);
  int cb = 0;
  for (int kt = 0; kt < 15; ++kt) {
    const int nb = cb ^ 8192;
#pragma unroll
    for (int j = 0; j < 2; ++j) gl_lds16(srcB[j] + (kt + 1) * 64, Bs + nb + offB[j]);
    asm volatile("s_waitcnt vmcnt(2)" ::: "memory");   // tile kt done, tile kt+1 in flight
    __builtin_amdgcn_s_barrier();
    __builtin_amdgcn_sched_barrier(0);
#pragma unroll
    for (int ph = 0; ph < 2; ++ph) {
      const int sc = ((ph * 4 + lh) ^ (lr & 7)) * 16;
      f16x8 af = *(const f16x8*)(LP + lr * 2048 + kt * 128 + sc);
      f16x8 bf = *(const f16x8*)(Bs + cb + (wid * 16 + lr) * 128 + sc);
      acc = __builtin_amdgcn_mfma_f32_16x16x32_f16(af, bf, acc, 0, 0, 0);
    }
    __builtin_amdgcn_sched_barrier(0);
    __builtin_amdgcn_s_barrier();                      // WAR guard
    __builtin_amdgcn_sched_barrier(0);
    cb = nb;
  }
  asm volatile("s_waitcnt vmcnt(0)" ::: "memory");
  __builtin_amdgcn_s_barrier();
  __builtin_amdgcn_sched_barrier(0);
#pragma unroll
  for (int ph = 0; ph < 2; ++ph) {
    const int sc = ((ph * 4 + lh) ^ (lr & 7)) * 16;
    f16x8 af = *(const f16x8*)(LP + lr * 2048 + 15 * 128 + sc);
    f16x8 bf = *(const f16x8*)(Bs + cb + (wid * 16 + lr) * 128 + sc);
    acc = __builtin_amdgcn_mfma_f32_16x16x32_f16(af, bf, acc, 0, 0, 0);
  }
  // C/D: col=lane&15, row=lh*4+reg
#pragma unroll
  for (int r = 0; r < 4; ++r)
    out[(size_t)(m0 + lh * 4 + r) * 64 + wid * 16 + lr] = acc[r];
}

extern "C" void kernel_launch(void* const* d_in, const int* in_sizes, int n_in,
                              void* d_out, int out_size, void* d_ws, size_t ws_size,
                              hipStream_t stream) {
  const float* feat = (const float*)d_in[0];
  const float* W    = (const float*)d_in[1];
  const float* bv   = (const float*)d_in[2];
  const float* LL   = (const float*)d_in[3];
  float* out = (float*)d_out;
  char* ws = (char*)d_ws;

  // ws layout (bytes): fA 16MiB @0 | Wt 2MiB @16MiB | LLt @18MiB | pq 32MiB @19MiB
  _Float16* fA  = (_Float16*)(ws);
  _Float16* Wt  = (_Float16*)(ws + (size_t)(16u << 20));
  _Float16* LLt = (_Float16*)(ws + (size_t)(18u << 20));
  uint32_t* pq  = (uint32_t*)(ws + (size_t)(19u << 20));

  k_prep <<<4416, 256, 0, stream>>>(feat, W, LL, fA, Wt, LLt);
  k_gemm1<<<512,  256, 0, stream>>>(fA, Wt, bv, pq);
  k_out  <<<512,  256, 0, stream>>>(pq, LLt, out);
}